// Round 5
// baseline (13002.168 us; speedup 1.0000x reference)
//
#include <hip/hip_runtime.h>
#include <hip/hip_bf16.h>
#include <math.h>

// ---------------------------------------------------------------------------
// SuperPoint point head, f64 end-to-end (NMS exact-equality requires score
// ordering identical to the float64 numpy reference).
// Round 5: revert to the PASSING round-3 VALU convs; add an in-stream MFMA
// layout probe (4 variants vs VALU ground truth). Wrong variants trigger
// long 'mfma_vK_bad' delay kernels -> visible in rocprof top-5.
// ---------------------------------------------------------------------------

#define B_      16
#define HC      60
#define WC      80
#define PIX     (HC * WC)          // 4800
#define HF      480
#define WF      640
#define IMG     (HF * WF)          // 307200
#define NPIX    (B_ * IMG)         // 4915200

typedef double f64x4 __attribute__((ext_vector_type(4)));

__device__ __forceinline__ int clampi(int v, int lo, int hi) {
    return v < lo ? lo : (v > hi ? hi : v);
}

// ---------------------------------------------------------------------------
__global__ __launch_bounds__(256) void cvt_f32_f64(const float* __restrict__ s,
                                                   double* __restrict__ d, int n)
{
    int i = blockIdx.x * 256 + threadIdx.x;
    if (i < n) d[i] = (double)s[i];
}

// Weight pre-transform for the MFMA probe: w[oc][ic][3][3] f32 -> f64
// [ocb][chk][dydx][ick][ocl].  Launched with n=73728 -> covers ocb 0 only.
__global__ __launch_bounds__(256) void prep_w(const float* __restrict__ w,
                                              double* __restrict__ wT,
                                              int CIN, int n)
{
    int i = blockIdx.x * 256 + threadIdx.x;
    if (i >= n) return;
    int cin9 = CIN * 9;
    int oc   = i / cin9;
    int rem  = i - oc * cin9;
    int ic   = rem / 9;
    int dydx = rem - ic * 9;
    size_t dst = ((size_t)((oc >> 4) * (CIN >> 2) + (ic >> 2)) * 9 + dydx) * 64
               + (ic & 3) * 16 + (oc & 15);
    wT[dst] = (double)w[i];
}

// ---------------------------------------------------------------------------
// conv 3x3, pad 1, + bias (+ReLU), f64 VALU accumulate.  (round-3, PASSING)
// ---------------------------------------------------------------------------
template <int CIN, typename TIN, bool RELU>
__global__ __launch_bounds__(256) void conv3x3_f64(
    const TIN* __restrict__ in,      // [G][CIN][60][80]
    const double* __restrict__ w,    // [COUT][CIN][3][3]
    const double* __restrict__ bias, // [COUT]
    double* __restrict__ out,        // [G][COUT][60][80]
    int COUT)
{
    const int ytile = blockIdx.x;          // 0..19
    const int oc0   = blockIdx.y * 16;
    const int b     = blockIdx.z;
    const int tid   = threadIdx.x;
    const int r     = tid / WC;            // 0..2 active, 3 idle for compute
    const int cx    = tid % WC;
    const int y0    = ytile * 3;

    in  += (size_t)b * CIN  * PIX;
    out += (size_t)b * COUT * PIX;

    __shared__ double sin_[4][5][82];

    double acc[16];
#pragma unroll
    for (int o = 0; o < 16; ++o) acc[o] = 0.0;

    for (int icc = 0; icc < CIN; icc += 4) {
        __syncthreads();
        for (int i = tid; i < 4 * 5 * 82; i += 256) {
            int ick = i / 410;
            int rem = i - ick * 410;
            int ry  = rem / 82, rx = rem - ry * 82;
            int gy  = y0 - 1 + ry, gx = rx - 1;
            double v = 0.0;
            if ((unsigned)gy < (unsigned)HC && (unsigned)gx < (unsigned)WC)
                v = (double)in[(size_t)(icc + ick) * PIX + gy * WC + gx];
            sin_[ick][ry][rx] = v;
        }
        __syncthreads();

        if (r < 3) {
            for (int k = 0; k < 4; ++k) {
                const int ic = icc + k;
                double v00 = sin_[k][r + 0][cx + 0], v01 = sin_[k][r + 0][cx + 1], v02 = sin_[k][r + 0][cx + 2];
                double v10 = sin_[k][r + 1][cx + 0], v11 = sin_[k][r + 1][cx + 1], v12 = sin_[k][r + 1][cx + 2];
                double v20 = sin_[k][r + 2][cx + 0], v21 = sin_[k][r + 2][cx + 1], v22 = sin_[k][r + 2][cx + 2];
                const double* wp = w + ((size_t)oc0 * CIN + ic) * 9;
#pragma unroll
                for (int o = 0; o < 16; ++o) {
                    const double* wo = wp + (size_t)o * CIN * 9;
                    acc[o] += v00 * wo[0] + v01 * wo[1] + v02 * wo[2]
                            + v10 * wo[3] + v11 * wo[4] + v12 * wo[5]
                            + v20 * wo[6] + v21 * wo[7] + v22 * wo[8];
                }
            }
        }
    }

    if (r < 3) {
        int y = y0 + r;
        double* ob = out + (size_t)y * WC + cx;
#pragma unroll
        for (int o = 0; o < 16; ++o) {
            double v = acc[o] + bias[oc0 + o];
            if (RELU) v = fmax(v, 0.0);
            ob[(size_t)(oc0 + o) * PIX] = v;
        }
    }
}

// ---------------------------------------------------------------------------
// MFMA layout probe: identical staging to the round-4 MFMA conv, one block,
// ytile 0 / ocb 0 / one batch.  Compares 5120 outputs vs VALU h1.
// VAR 0: A=w(m=l&15,k=l>>4) B=act(n=l&15,k=l>>4)  D: oc=4q+i, px=c
// VAR 1: same operands, D transposed:              oc=c, px=4q+i
// VAR 2: mfma(act, w):                             oc=c, px=4q+i
// VAR 3: V0 operands, D row=q+4i:                  oc=q+4i, px=c
// ---------------------------------------------------------------------------
template <int VAR>
__global__ __launch_bounds__(256) void probe_mfma(
    const float* __restrict__ in,     // [512][4800] batch b0
    const double* __restrict__ wT,    // ocb0: [128][9][4][16]
    const double* __restrict__ bias,  // [256]
    const double* __restrict__ href,  // [256][4800] VALU h1 batch b0
    int* __restrict__ cnt)
{
    const int tid  = threadIdx.x;
    const int wv   = tid >> 6;
    const int lane = tid & 63;
    const int q    = lane >> 4;
    const int c    = lane & 15;

    __shared__ double smem[4 * 6 * 82 + 9 * 64];
    double* act = smem;
    double* wl  = smem + 1968;

    f64x4 acc[5];
#pragma unroll
    for (int t = 0; t < 5; ++t) acc[t] = (f64x4){0.0, 0.0, 0.0, 0.0};

    const int bbase = q * 492 + wv * 82 + c;

    for (int chk = 0; chk < 128; ++chk) {
        __syncthreads();
#pragma unroll
        for (int j = 0; j < 8; ++j) {
            int i = tid + j * 256;
            if (i < 1968) {
                int ick = i / 492;
                int rem = i - ick * 492;
                int ry  = rem / 82;
                int rx  = rem - ry * 82;
                int gy  = -1 + ry, gx = rx - 1;
                double v = 0.0;
                if ((unsigned)gy < (unsigned)HC && (unsigned)gx < (unsigned)WC)
                    v = (double)in[(size_t)(chk * 4 + ick) * PIX + gy * WC + gx];
                act[i] = v;
            }
        }
        {
            const double* wsrc = wT + (size_t)chk * 576;
#pragma unroll
            for (int j = 0; j < 3; ++j) {
                int i = tid + j * 256;
                if (i < 576) wl[i] = wsrc[i];
            }
        }
        __syncthreads();

#pragma unroll
        for (int dy = 0; dy < 3; ++dy) {
#pragma unroll
            for (int dx = 0; dx < 3; ++dx) {
                const int dydx = dy * 3 + dx;
                double a = wl[dydx * 64 + lane];
#pragma unroll
                for (int t = 0; t < 5; ++t) {
                    double bv = act[bbase + dy * 82 + t * 16 + dx];
                    if (VAR == 2)
                        acc[t] = __builtin_amdgcn_mfma_f64_16x16x4f64(bv, a, acc[t], 0, 0, 0);
                    else
                        acc[t] = __builtin_amdgcn_mfma_f64_16x16x4f64(a, bv, acc[t], 0, 0, 0);
                }
            }
        }
    }

    int bad = 0;
    const int y = wv;
#pragma unroll
    for (int t = 0; t < 5; ++t) {
#pragma unroll
        for (int i = 0; i < 4; ++i) {
            int oc, px;
            if (VAR == 0)      { oc = q * 4 + i; px = t * 16 + c; }
            else if (VAR == 3) { oc = q + 4 * i; px = t * 16 + c; }
            else               { oc = c;         px = t * 16 + q * 4 + i; }
            double v = fmax(acc[t][i] + bias[oc], 0.0);
            double r = href[(size_t)oc * PIX + y * WC + px];
            double d = v - r;
            bool ok = fabs(d) <= 1e-9 + 1e-9 * fabs(r);
            if (!ok) ++bad;
        }
    }
    if (bad) atomicAdd(cnt, bad);
}

__global__ void zero_cnt(int* c)
{
    if (threadIdx.x < 4) c[threadIdx.x] = 0;
}

// Delay kernels: fire (long dependent-FMA chain) iff their variant mismatched.
__global__ void mfma_v0_bad(const int* cnt, double* sink)
{
    if (cnt[0] == 0) return;
    double xv = 1.0;
    for (int i = 0; i < 1500000; ++i) xv = fma(xv, 1.0000000001, 1e-300);
    if (threadIdx.x == 0) sink[0] = xv;
}
__global__ void mfma_v1_bad(const int* cnt, double* sink)
{
    if (cnt[1] == 0) return;
    double xv = 1.0;
    for (int i = 0; i < 1800000; ++i) xv = fma(xv, 1.0000000001, 1e-300);
    if (threadIdx.x == 0) sink[1] = xv;
}
__global__ void mfma_v2_bad(const int* cnt, double* sink)
{
    if (cnt[2] == 0) return;
    double xv = 1.0;
    for (int i = 0; i < 2100000; ++i) xv = fma(xv, 1.0000000001, 1e-300);
    if (threadIdx.x == 0) sink[2] = xv;
}
__global__ void mfma_v3_bad(const int* cnt, double* sink)
{
    if (cnt[3] == 0) return;
    double xv = 1.0;
    for (int i = 0; i < 2400000; ++i) xv = fma(xv, 1.0000000001, 1e-300);
    if (threadIdx.x == 0) sink[3] = xv;
}

// ---------------------------------------------------------------------------
// conv1x1 (128->65) + softmax(65)[:64] + pixel-unshuffle.  grid (19, G).
// ---------------------------------------------------------------------------
__global__ __launch_bounds__(256) void conv1x1_softmax_f64(
    const double* __restrict__ h2,
    const double* __restrict__ wg,
    const double* __restrict__ bg,
    double* __restrict__ S)
{
    int p = blockIdx.x * 256 + threadIdx.x;
    if (p >= PIX) return;
    const int b = blockIdx.y;
    const double* h2p = h2 + (size_t)b * 128 * PIX + p;
    double* Sb = S + (size_t)b * IMG;

    double l[65];
#pragma unroll
    for (int o = 0; o < 65; ++o) l[o] = bg[o];

    for (int icc = 0; icc < 128; icc += 8) {
        double h[8];
#pragma unroll
        for (int k = 0; k < 8; ++k) h[k] = h2p[(size_t)(icc + k) * PIX];
#pragma unroll
        for (int o = 0; o < 65; ++o) {
            const double* wp = wg + o * 128 + icc;
            l[o] += h[0] * wp[0] + h[1] * wp[1] + h[2] * wp[2] + h[3] * wp[3]
                  + h[4] * wp[4] + h[5] * wp[5] + h[6] * wp[6] + h[7] * wp[7];
        }
    }

    double m = l[0];
#pragma unroll
    for (int o = 1; o < 65; ++o) m = fmax(m, l[o]);
    double s = 0.0;
#pragma unroll
    for (int o = 0; o < 65; ++o) { l[o] = exp(l[o] - m); s += l[o]; }
    double inv = 1.0 / s;

    int y = p / WC, x = p % WC;
#pragma unroll
    for (int cy = 0; cy < 8; ++cy)
#pragma unroll
        for (int cx2 = 0; cx2 < 8; ++cx2)
            Sb[(y * 8 + cy) * WF + x * 8 + cx2] = l[cy * 8 + cx2] * inv;
}

// ---------------------------------------------------------------------------
// NMS passes on f64 scores.
// ---------------------------------------------------------------------------
__global__ __launch_bounds__(256) void hmax9_f64(const double* __restrict__ in,
                                                 double* __restrict__ out)
{
    int p = blockIdx.x * 256 + threadIdx.x;
    int x = p % WF;
    const double* row = in + (p - x);
    double m = row[x];
#pragma unroll
    for (int d = 1; d <= 4; ++d) {
        m = fmax(m, row[clampi(x - d, 0, WF - 1)]);
        m = fmax(m, row[clampi(x + d, 0, WF - 1)]);
    }
    out[p] = m;
}

__global__ __launch_bounds__(256) void vmax9_eq(const double* __restrict__ T,
                                                const double* __restrict__ S,
                                                unsigned char* __restrict__ M)
{
    int p = blockIdx.x * 256 + threadIdx.x;
    int y = (p % IMG) / WF;
    double m = T[p];
#pragma unroll
    for (int d = 1; d <= 4; ++d) {
        m = fmax(m, T[p + (clampi(y - d, 0, HF - 1) - y) * WF]);
        m = fmax(m, T[p + (clampi(y + d, 0, HF - 1) - y) * WF]);
    }
    M[p] = (S[p] == m) ? (unsigned char)1 : (unsigned char)0;
}

__global__ __launch_bounds__(256) void hor9_u8(const unsigned char* __restrict__ in,
                                               unsigned char* __restrict__ out)
{
    int p = blockIdx.x * 256 + threadIdx.x;
    int x = p % WF;
    const unsigned char* row = in + (p - x);
    unsigned char m = row[x];
#pragma unroll
    for (int d = 1; d <= 4; ++d) {
        m = m | row[clampi(x - d, 0, WF - 1)];
        m = m | row[clampi(x + d, 0, WF - 1)];
    }
    out[p] = m;
}

__global__ __launch_bounds__(256) void vor9_sup(const unsigned char* __restrict__ T8,
                                                unsigned char* __restrict__ SUP)
{
    int p = blockIdx.x * 256 + threadIdx.x;
    int y = (p % IMG) / WF;
    unsigned char m = T8[p];
#pragma unroll
    for (int d = 1; d <= 4; ++d) {
        m = m | T8[p + (clampi(y - d, 0, HF - 1) - y) * WF];
        m = m | T8[p + (clampi(y + d, 0, HF - 1) - y) * WF];
    }
    SUP[p] = m;
}

__global__ __launch_bounds__(256) void hmax9_supp(const double* __restrict__ S,
                                                  const unsigned char* __restrict__ SUP,
                                                  double* __restrict__ T)
{
    int p = blockIdx.x * 256 + threadIdx.x;
    int x = p % WF;
    int base = p - x;
    double m = SUP[p] ? 0.0 : S[p];
#pragma unroll
    for (int d = 1; d <= 4; ++d) {
        int i1 = base + clampi(x - d, 0, WF - 1);
        int i2 = base + clampi(x + d, 0, WF - 1);
        m = fmax(m, SUP[i1] ? 0.0 : S[i1]);
        m = fmax(m, SUP[i2] ? 0.0 : S[i2]);
    }
    T[p] = m;
}

__global__ __launch_bounds__(256) void vmax9_newmask(const double* __restrict__ T,
                                                     const double* __restrict__ S,
                                                     const unsigned char* __restrict__ SUP,
                                                     unsigned char* __restrict__ M)
{
    int p = blockIdx.x * 256 + threadIdx.x;
    int y = (p % IMG) / WF;
    double m = T[p];
#pragma unroll
    for (int d = 1; d <= 4; ++d) {
        m = fmax(m, T[p + (clampi(y - d, 0, HF - 1) - y) * WF]);
        m = fmax(m, T[p + (clampi(y + d, 0, HF - 1) - y) * WF]);
    }
    unsigned char nw = (!SUP[p] && S[p] == m) ? 1 : 0;
    M[p] = M[p] | nw;
}

__global__ __launch_bounds__(256) void final_mask(const double* __restrict__ S,
                                                  const unsigned char* __restrict__ M,
                                                  float* __restrict__ out)
{
    int p = blockIdx.x * 256 + threadIdx.x;
    out[p] = M[p] ? (float)S[p] : 0.f;
}

// ---------------------------------------------------------------------------
extern "C" void kernel_launch(void* const* d_in, const int* in_sizes, int n_in,
                              void* d_out, int out_size, void* d_ws, size_t ws_size,
                              hipStream_t stream)
{
    const float* x   = (const float*)d_in[0];
    const float* wPa = (const float*)d_in[1];
    const float* bPa = (const float*)d_in[2];
    const float* wPd = (const float*)d_in[3];
    const float* bPd = (const float*)d_in[4];
    const float* wPg = (const float*)d_in[5];
    const float* bPg = (const float*)d_in[6];
    float* out = (float*)d_out;

    char* ws = (char*)d_ws;
    // ---- persistent / NMS-phase layout -------------------------------------
    double*        S   = (double*)(ws);                        // 39,321,600
    double*        T   = (double*)(ws + 39321600);             // 39,321,600
    unsigned char* M   = (unsigned char*)(ws + 78643200);      //  4,915,200
    unsigned char* SUP = (unsigned char*)(ws + 83558400);      //  4,915,200
    unsigned char* T8  = (unsigned char*)(ws + 88473600);      //  4,915,200
    // ---- conv-phase overlay (inside T region, dead until NMS) --------------
    double* w1d = (double*)(ws + 39321600);   // 9,437,184 (original layout f64)
    double* w2d = (double*)(ws + 48758784);   // 2,359,296
    double* wgd = (double*)(ws + 51118080);   // 66,560
    double* b1d = (double*)(ws + 51184640);   // 2,048
    double* b2d = (double*)(ws + 51186688);   // 1,024
    double* bgd = (double*)(ws + 51187712);   // 1,024 (pad)
    char*   hbase = ws + 51188736;            // batch-group h1/h2 area

    int G = 1;
    for (int g = 16; g >= 1; g >>= 1) {
        if ((size_t)51188736 + (size_t)g * 14745600 <= ws_size) { G = g; break; }
    }

    // weights -> f64 (original layout; VALU convs)
    cvt_f32_f64<<<(1179648 + 255) / 256, 256, 0, stream>>>(wPa, w1d, 1179648);
    cvt_f32_f64<<<(294912 + 255) / 256, 256, 0, stream>>>(wPd, w2d, 294912);
    cvt_f32_f64<<<(8320 + 255) / 256, 256, 0, stream>>>(wPg, wgd, 8320);
    cvt_f32_f64<<<1, 256, 0, stream>>>(bPa, b1d, 256);
    cvt_f32_f64<<<1, 256, 0, stream>>>(bPd, b2d, 128);
    cvt_f32_f64<<<1, 256, 0, stream>>>(bPg, bgd, 65);

    int b0_last = 0;
    for (int bg0 = 0; bg0 < B_; bg0 += G) {
        int Gc = (bg0 + G <= B_) ? G : (B_ - bg0);
        b0_last = bg0;
        double* h1s = (double*)hbase;
        double* h2s = (double*)(hbase + (size_t)G * 9830400);
        const float* xb = x + (size_t)bg0 * 512 * PIX;
        conv3x3_f64<512, float, true><<<dim3(20, 16, Gc), 256, 0, stream>>>(xb, w1d, b1d, h1s, 256);
        conv3x3_f64<256, double, true><<<dim3(20, 8, Gc), 256, 0, stream>>>(h1s, w2d, b2d, h2s, 128);
        conv1x1_softmax_f64<<<dim3(19, Gc), 256, 0, stream>>>(h2s, wgd, bgd, S + (size_t)bg0 * IMG);
    }

    // ---- MFMA layout probes (after all conv reads of w2d/h2s are done) -----
    // probe weight transform reuses the w2d region (dead now): ocb 0 only.
    double* w1t_probe = w2d;                  // 73,728 f64 = 589,824 B, fits
    // counters/sink live in the dead tail of h2s (read-complete above).
    char* cnt_base = hbase + (size_t)G * 9830400 + (size_t)G * 4915200 - 4096;
    int*    cnt  = (int*)cnt_base;
    double* sink = (double*)(cnt_base + 64);

    prep_w<<<(73728 + 255) / 256, 256, 0, stream>>>(wPa, w1t_probe, 512, 73728);
    zero_cnt<<<1, 64, 0, stream>>>(cnt);
    {
        const float* xb0   = x + (size_t)b0_last * 512 * PIX;   // last group's batch 0
        const double* href = (const double*)hbase;              // its VALU h1
        probe_mfma<0><<<1, 256, 0, stream>>>(xb0, w1t_probe, b1d, href, cnt);
        probe_mfma<1><<<1, 256, 0, stream>>>(xb0, w1t_probe, b1d, href, cnt);
        probe_mfma<2><<<1, 256, 0, stream>>>(xb0, w1t_probe, b1d, href, cnt);
        probe_mfma<3><<<1, 256, 0, stream>>>(xb0, w1t_probe, b1d, href, cnt);
    }

    // ---- NMS (writes only ws[0 .. 93,388,800) — counters at h2s tail safe) -
    const int NB = NPIX / 256;  // 19200
    hmax9_f64<<<NB, 256, 0, stream>>>(S, T);
    vmax9_eq<<<NB, 256, 0, stream>>>(T, S, M);
    for (int it = 0; it < 2; ++it) {
        hor9_u8<<<NB, 256, 0, stream>>>(M, T8);
        vor9_sup<<<NB, 256, 0, stream>>>(T8, SUP);
        hmax9_supp<<<NB, 256, 0, stream>>>(S, SUP, T);
        vmax9_newmask<<<NB, 256, 0, stream>>>(T, S, SUP, M);
    }
    final_mask<<<NB, 256, 0, stream>>>(S, M, out);

    // ---- probe readout: wrong variants burn a visible, distinct delay ------
    mfma_v0_bad<<<1, 64, 0, stream>>>(cnt, sink);
    mfma_v1_bad<<<1, 64, 0, stream>>>(cnt, sink);
    mfma_v2_bad<<<1, 64, 0, stream>>>(cnt, sink);
    mfma_v3_bad<<<1, 64, 0, stream>>>(cnt, sink);
}

// Round 6
// 5427.479 us; speedup vs baseline: 2.3956x; 2.3956x over previous
//
#include <hip/hip_runtime.h>
#include <hip/hip_bf16.h>
#include <math.h>

// ---------------------------------------------------------------------------
// SuperPoint point head, f64 end-to-end (NMS exact-equality requires score
// ordering identical to the float64 numpy reference).
// Round 6: 3x3 convs on v_mfma_f64_16x16x4_f64 with a RUNTIME-LEARNED D
// fragment map: two register-only probe MFMAs per wave encode code=16*row+col
// for each (lane, acc-reg), and the epilogue scatters accordingly.  This is
// robust to any lane->(row,col) D permutation and to arg-order conventions
// (round-4's hardcoded canonical map failed; round-5's probe readout was
// burned by an atomicAdd(cnt)-not-cnt[VAR] bug, so we stop guessing).
// ---------------------------------------------------------------------------

#define B_      16
#define HC      60
#define WC      80
#define PIX     (HC * WC)          // 4800
#define HF      480
#define WF      640
#define IMG     (HF * WF)          // 307200
#define NPIX    (B_ * IMG)         // 4915200

typedef double f64x4 __attribute__((ext_vector_type(4)));

__device__ __forceinline__ int clampi(int v, int lo, int hi) {
    return v < lo ? lo : (v > hi ? hi : v);
}

// ---------------------------------------------------------------------------
__global__ __launch_bounds__(256) void cvt_f32_f64(const float* __restrict__ s,
                                                   double* __restrict__ d, int n)
{
    int i = blockIdx.x * 256 + threadIdx.x;
    if (i < n) d[i] = (double)s[i];
}

// Weight pre-transform: w[oc][ic][3][3] f32 -> wT f64 laid out as
// [ocb][chk][dydx][ick][ocl]  (ocb=oc/16, ocl=oc%16, chk=ic/4, ick=ic%4)
__global__ __launch_bounds__(256) void prep_w(const float* __restrict__ w,
                                              double* __restrict__ wT,
                                              int CIN, int n)
{
    int i = blockIdx.x * 256 + threadIdx.x;
    if (i >= n) return;
    int cin9 = CIN * 9;
    int oc   = i / cin9;
    int rem  = i - oc * cin9;
    int ic   = rem / 9;
    int dydx = rem - ic * 9;
    size_t dst = ((size_t)((oc >> 4) * (CIN >> 2) + (ic >> 2)) * 9 + dydx) * 64
               + (ic & 3) * 16 + (oc & 15);
    wT[dst] = (double)w[i];
}

// ---------------------------------------------------------------------------
// conv 3x3 pad 1 + bias + ReLU via v_mfma_f64_16x16x4_f64, self-learned D map.
// block 256 = 4 waves; wave wv -> output row y0+wv; 5 px-tiles of 16.
// grid: (15 ytiles, COUT/16, G batches).  Per 4-ic chunk: stage act [4][6][82]
// + weights [9][4][16] in LDS, then 9 (dy,dx) x 5 tiles MFMAs per wave.
// arg1 lane l <- w[oc0 + (l&15)][chk*4 + (l>>4)][dydx]
// arg2 lane l <- act[chk*4 + (l>>4)][row wv+dy][col (l&15) + t*16 + dx]
// acc(l,i) = conv[oc0 + X(l,i)][px t*16 + Y(l,i)]  with (X,Y) learned below.
// ---------------------------------------------------------------------------
template <int CIN, typename TIN, bool RELU>
__global__ __launch_bounds__(256) void conv3x3_mfma(
    const TIN* __restrict__ in,      // [G][CIN][60][80]
    const double* __restrict__ wT,   // transformed, see prep_w
    const double* __restrict__ bias, // [COUT]
    double* __restrict__ out)        // [G][COUT][60][80]
{
    const int COUT  = (CIN == 512) ? 256 : 128;
    const int ytile = blockIdx.x;          // 0..14 (4 rows each)
    const int ocb   = blockIdx.y;
    const int oc0   = ocb * 16;
    const int b     = blockIdx.z;
    const int tid   = threadIdx.x;
    const int wv    = tid >> 6;            // wave -> output row
    const int lane  = tid & 63;
    const int q     = lane >> 4;
    const int c     = lane & 15;
    const int y0    = ytile * 4;

    in  += (size_t)b * CIN  * PIX;
    out += (size_t)b * COUT * PIX;

    // ---- self-learn the D fragment map: code(l,i) = 16*X + Y ---------------
    // Probe 1: arg1 = "W" with W[m][0]=16m, arg2 = "Act" with Act[0][n]=1
    // Probe 2: W[m][0]=1, Act[0][n]=n.   acc = 16*X + Y exactly (f64 exact).
    int rowL[4], colL[4];
    {
        f64x4 pr = (f64x4){0.0, 0.0, 0.0, 0.0};
        double a1 = (lane < 16) ? (double)(16 * lane) : 0.0;
        double b1 = (lane < 16) ? 1.0 : 0.0;
        pr = __builtin_amdgcn_mfma_f64_16x16x4f64(a1, b1, pr, 0, 0, 0);
        double a2 = (lane < 16) ? 1.0 : 0.0;
        double b2 = (lane < 16) ? (double)lane : 0.0;
        pr = __builtin_amdgcn_mfma_f64_16x16x4f64(a2, b2, pr, 0, 0, 0);
#pragma unroll
        for (int i = 0; i < 4; ++i) {
            int code = (int)pr[i];
            rowL[i] = (code >> 4) & 15;   // mask: never OOB even if map-form odd
            colL[i] = code & 15;
        }
    }

    __shared__ double smem[4 * 6 * 82 + 9 * 64];   // act 1968 + w 576
    double* act = smem;
    double* wl  = smem + 1968;

    f64x4 acc[5];
#pragma unroll
    for (int t = 0; t < 5; ++t) acc[t] = (f64x4){0.0, 0.0, 0.0, 0.0};

    const int bbase = q * 492 + wv * 82 + c;

    const int NCH = CIN / 4;
    const double* wchunk = wT + (size_t)ocb * NCH * 576;

    for (int chk = 0; chk < NCH; ++chk) {
        __syncthreads();
        // ---- stage activations: 4 ic x rows (y0-1 .. y0+4) x cols (-1..80)
#pragma unroll
        for (int j = 0; j < 8; ++j) {
            int i = tid + j * 256;
            if (i < 1968) {
                int ick = i / 492;
                int rem = i - ick * 492;
                int ry  = rem / 82;
                int rx  = rem - ry * 82;
                int gy  = y0 - 1 + ry, gx = rx - 1;
                double v = 0.0;
                if ((unsigned)gy < (unsigned)HC && (unsigned)gx < (unsigned)WC)
                    v = (double)in[(size_t)(chk * 4 + ick) * PIX + gy * WC + gx];
                act[i] = v;
            }
        }
        // ---- stage weights: linear 576-f64 coalesced copy
        {
            const double* wsrc = wchunk + (size_t)chk * 576;
#pragma unroll
            for (int j = 0; j < 3; ++j) {
                int i = tid + j * 256;
                if (i < 576) wl[i] = wsrc[i];
            }
        }
        __syncthreads();

        // ---- 9 (dy,dx) x 5 px-tiles MFMAs
#pragma unroll
        for (int dy = 0; dy < 3; ++dy) {
#pragma unroll
            for (int dx = 0; dx < 3; ++dx) {
                const int dydx = dy * 3 + dx;
                double a = wl[dydx * 64 + lane];
#pragma unroll
                for (int t = 0; t < 5; ++t) {
                    double bv = act[bbase + dy * 82 + t * 16 + dx];
                    acc[t] = __builtin_amdgcn_mfma_f64_16x16x4f64(a, bv, acc[t], 0, 0, 0);
                }
            }
        }
    }

    // ---- epilogue: scatter via learned (X,Y), bias + ReLU ------------------
    const int y = y0 + wv;
#pragma unroll
    for (int t = 0; t < 5; ++t) {
#pragma unroll
        for (int i = 0; i < 4; ++i) {
            const int oc = oc0 + rowL[i];
            double v = acc[t][i] + bias[oc];
            if (RELU) v = fmax(v, 0.0);
            out[(size_t)oc * PIX + y * WC + t * 16 + colL[i]] = v;
        }
    }
}

// ---------------------------------------------------------------------------
// conv1x1 (128->65) + softmax(65)[:64] + pixel-unshuffle.  grid (19, G).
// ---------------------------------------------------------------------------
__global__ __launch_bounds__(256) void conv1x1_softmax_f64(
    const double* __restrict__ h2,   // [G][128][4800]
    const double* __restrict__ wg,   // [65][128]
    const double* __restrict__ bg,   // [65]
    double* __restrict__ S)          // [G][480][640]
{
    int p = blockIdx.x * 256 + threadIdx.x;
    if (p >= PIX) return;
    const int b = blockIdx.y;
    const double* h2p = h2 + (size_t)b * 128 * PIX + p;
    double* Sb = S + (size_t)b * IMG;

    double l[65];
#pragma unroll
    for (int o = 0; o < 65; ++o) l[o] = bg[o];

    for (int icc = 0; icc < 128; icc += 8) {
        double h[8];
#pragma unroll
        for (int k = 0; k < 8; ++k) h[k] = h2p[(size_t)(icc + k) * PIX];
#pragma unroll
        for (int o = 0; o < 65; ++o) {
            const double* wp = wg + o * 128 + icc;
            l[o] += h[0] * wp[0] + h[1] * wp[1] + h[2] * wp[2] + h[3] * wp[3]
                  + h[4] * wp[4] + h[5] * wp[5] + h[6] * wp[6] + h[7] * wp[7];
        }
    }

    double m = l[0];
#pragma unroll
    for (int o = 1; o < 65; ++o) m = fmax(m, l[o]);
    double s = 0.0;
#pragma unroll
    for (int o = 0; o < 65; ++o) { l[o] = exp(l[o] - m); s += l[o]; }
    double inv = 1.0 / s;

    int y = p / WC, x = p % WC;
#pragma unroll
    for (int cy = 0; cy < 8; ++cy)
#pragma unroll
        for (int cx2 = 0; cx2 < 8; ++cx2)
            Sb[(y * 8 + cy) * WF + x * 8 + cx2] = l[cy * 8 + cx2] * inv;
}

// ---------------------------------------------------------------------------
// NMS passes on f64 scores (equality decisions must be f64-exact).
// ---------------------------------------------------------------------------
__global__ __launch_bounds__(256) void hmax9_f64(const double* __restrict__ in,
                                                 double* __restrict__ out)
{
    int p = blockIdx.x * 256 + threadIdx.x;
    int x = p % WF;
    const double* row = in + (p - x);
    double m = row[x];
#pragma unroll
    for (int d = 1; d <= 4; ++d) {
        m = fmax(m, row[clampi(x - d, 0, WF - 1)]);
        m = fmax(m, row[clampi(x + d, 0, WF - 1)]);
    }
    out[p] = m;
}

__global__ __launch_bounds__(256) void vmax9_eq(const double* __restrict__ T,
                                                const double* __restrict__ S,
                                                unsigned char* __restrict__ M)
{
    int p = blockIdx.x * 256 + threadIdx.x;
    int y = (p % IMG) / WF;
    double m = T[p];
#pragma unroll
    for (int d = 1; d <= 4; ++d) {
        m = fmax(m, T[p + (clampi(y - d, 0, HF - 1) - y) * WF]);
        m = fmax(m, T[p + (clampi(y + d, 0, HF - 1) - y) * WF]);
    }
    M[p] = (S[p] == m) ? (unsigned char)1 : (unsigned char)0;
}

__global__ __launch_bounds__(256) void hor9_u8(const unsigned char* __restrict__ in,
                                               unsigned char* __restrict__ out)
{
    int p = blockIdx.x * 256 + threadIdx.x;
    int x = p % WF;
    const unsigned char* row = in + (p - x);
    unsigned char m = row[x];
#pragma unroll
    for (int d = 1; d <= 4; ++d) {
        m = m | row[clampi(x - d, 0, WF - 1)];
        m = m | row[clampi(x + d, 0, WF - 1)];
    }
    out[p] = m;
}

__global__ __launch_bounds__(256) void vor9_sup(const unsigned char* __restrict__ T8,
                                                unsigned char* __restrict__ SUP)
{
    int p = blockIdx.x * 256 + threadIdx.x;
    int y = (p % IMG) / WF;
    unsigned char m = T8[p];
#pragma unroll
    for (int d = 1; d <= 4; ++d) {
        m = m | T8[p + (clampi(y - d, 0, HF - 1) - y) * WF];
        m = m | T8[p + (clampi(y + d, 0, HF - 1) - y) * WF];
    }
    SUP[p] = m;
}

// horizontal max of (SUP ? 0 : S)
__global__ __launch_bounds__(256) void hmax9_supp(const double* __restrict__ S,
                                                  const unsigned char* __restrict__ SUP,
                                                  double* __restrict__ T)
{
    int p = blockIdx.x * 256 + threadIdx.x;
    int x = p % WF;
    int base = p - x;
    double m = SUP[p] ? 0.0 : S[p];
#pragma unroll
    for (int d = 1; d <= 4; ++d) {
        int i1 = base + clampi(x - d, 0, WF - 1);
        int i2 = base + clampi(x + d, 0, WF - 1);
        m = fmax(m, SUP[i1] ? 0.0 : S[i1]);
        m = fmax(m, SUP[i2] ? 0.0 : S[i2]);
    }
    T[p] = m;
}

__global__ __launch_bounds__(256) void vmax9_newmask(const double* __restrict__ T,
                                                     const double* __restrict__ S,
                                                     const unsigned char* __restrict__ SUP,
                                                     unsigned char* __restrict__ M)
{
    int p = blockIdx.x * 256 + threadIdx.x;
    int y = (p % IMG) / WF;
    double m = T[p];
#pragma unroll
    for (int d = 1; d <= 4; ++d) {
        m = fmax(m, T[p + (clampi(y - d, 0, HF - 1) - y) * WF]);
        m = fmax(m, T[p + (clampi(y + d, 0, HF - 1) - y) * WF]);
    }
    unsigned char nw = (!SUP[p] && S[p] == m) ? 1 : 0;
    M[p] = M[p] | nw;
}

__global__ __launch_bounds__(256) void final_mask(const double* __restrict__ S,
                                                  const unsigned char* __restrict__ M,
                                                  float* __restrict__ out)
{
    int p = blockIdx.x * 256 + threadIdx.x;
    out[p] = M[p] ? (float)S[p] : 0.f;
}

// ---------------------------------------------------------------------------
extern "C" void kernel_launch(void* const* d_in, const int* in_sizes, int n_in,
                              void* d_out, int out_size, void* d_ws, size_t ws_size,
                              hipStream_t stream)
{
    const float* x   = (const float*)d_in[0];
    const float* wPa = (const float*)d_in[1];
    const float* bPa = (const float*)d_in[2];
    const float* wPd = (const float*)d_in[3];
    const float* bPd = (const float*)d_in[4];
    const float* wPg = (const float*)d_in[5];
    const float* bPg = (const float*)d_in[6];
    float* out = (float*)d_out;

    char* ws = (char*)d_ws;
    // ---- persistent / NMS-phase layout -------------------------------------
    double*        S   = (double*)(ws);                        // 39,321,600
    double*        T   = (double*)(ws + 39321600);             // 39,321,600
    unsigned char* M   = (unsigned char*)(ws + 78643200);      //  4,915,200
    unsigned char* SUP = (unsigned char*)(ws + 83558400);      //  4,915,200
    unsigned char* T8  = (unsigned char*)(ws + 88473600);      //  4,915,200
    // ---- conv-phase overlay (inside T region, dead until NMS) --------------
    double* w1t = (double*)(ws + 39321600);   // 256*512*9*8 = 9,437,184 (transformed)
    double* w2t = (double*)(ws + 48758784);   // 128*256*9*8 = 2,359,296 (transformed)
    double* wgd = (double*)(ws + 51118080);   // 65*128*8    =    66,560
    double* b1d = (double*)(ws + 51184640);   // 2,048
    double* b2d = (double*)(ws + 51186688);   // 1,024
    double* bgd = (double*)(ws + 51187712);   // 1,024 (pad)
    char*   hbase = ws + 51188736;            // batch-group h1/h2 area

    // largest batch-group G with 51,188,736 + G*14,745,600 <= ws_size
    // (round-3/5 runs confirmed G=16 fits: single-group conv dispatches)
    int G = 1;
    for (int g = 16; g >= 1; g >>= 1) {
        if ((size_t)51188736 + (size_t)g * 14745600 <= ws_size) { G = g; break; }
    }

    // weights -> f64, mfma layout for 3x3 convs
    prep_w<<<(1179648 + 255) / 256, 256, 0, stream>>>(wPa, w1t, 512, 1179648);
    prep_w<<<(294912 + 255) / 256, 256, 0, stream>>>(wPd, w2t, 256, 294912);
    cvt_f32_f64<<<(8320 + 255) / 256, 256, 0, stream>>>(wPg, wgd, 8320);
    cvt_f32_f64<<<1, 256, 0, stream>>>(bPa, b1d, 256);
    cvt_f32_f64<<<1, 256, 0, stream>>>(bPd, b2d, 128);
    cvt_f32_f64<<<1, 256, 0, stream>>>(bPg, bgd, 65);

    for (int bg0 = 0; bg0 < B_; bg0 += G) {
        int Gc = (bg0 + G <= B_) ? G : (B_ - bg0);
        double* h1s = (double*)hbase;                              // Gc*256*4800 f64
        double* h2s = (double*)(hbase + (size_t)G * 9830400);      // Gc*128*4800 f64
        const float* xb = x + (size_t)bg0 * 512 * PIX;
        conv3x3_mfma<512, float, true><<<dim3(15, 16, Gc), 256, 0, stream>>>(xb, w1t, b1d, h1s);
        conv3x3_mfma<256, double, true><<<dim3(15, 8, Gc), 256, 0, stream>>>(h1s, w2t, b2d, h2s);
        conv1x1_softmax_f64<<<dim3(19, Gc), 256, 0, stream>>>(h2s, wgd, bgd, S + (size_t)bg0 * IMG);
    }

    const int NB = NPIX / 256;  // 19200
    hmax9_f64<<<NB, 256, 0, stream>>>(S, T);
    vmax9_eq<<<NB, 256, 0, stream>>>(T, S, M);
    for (int it = 0; it < 2; ++it) {
        hor9_u8<<<NB, 256, 0, stream>>>(M, T8);
        vor9_sup<<<NB, 256, 0, stream>>>(T8, SUP);
        hmax9_supp<<<NB, 256, 0, stream>>>(S, SUP, T);
        vmax9_newmask<<<NB, 256, 0, stream>>>(T, S, SUP, M);
    }
    final_mask<<<NB, 256, 0, stream>>>(S, M, out);
}

// Round 7
// 5331.607 us; speedup vs baseline: 2.4387x; 1.0180x over previous
//
#include <hip/hip_runtime.h>
#include <hip/hip_bf16.h>
#include <math.h>

// ---------------------------------------------------------------------------
// SuperPoint point head, f64 end-to-end (NMS exact-equality requires score
// ordering identical to the float64 numpy reference).
// Round 7: conv3x3 MFMA kernel upgraded: 2 oc-blocks per block (B-operand
// reuse), double-buffered LDS, global loads for chunk k+1 issued before the
// MFMA phase of chunk k (latency hidden under ~1400cy of MFMA).
// D fragment map stays RUNTIME-LEARNED via 2 probe MFMAs (round-6 win).
// ---------------------------------------------------------------------------

#define B_      16
#define HC      60
#define WC      80
#define PIX     (HC * WC)          // 4800
#define HF      480
#define WF      640
#define IMG     (HF * WF)          // 307200
#define NPIX    (B_ * IMG)         // 4915200

typedef double f64x4 __attribute__((ext_vector_type(4)));

__device__ __forceinline__ int clampi(int v, int lo, int hi) {
    return v < lo ? lo : (v > hi ? hi : v);
}

// ---------------------------------------------------------------------------
__global__ __launch_bounds__(256) void cvt_f32_f64(const float* __restrict__ s,
                                                   double* __restrict__ d, int n)
{
    int i = blockIdx.x * 256 + threadIdx.x;
    if (i < n) d[i] = (double)s[i];
}

// Weight pre-transform: w[oc][ic][3][3] f32 -> wT f64 laid out as
// [ocb][chk][dydx][ick][ocl]  (ocb=oc/16, ocl=oc%16, chk=ic/4, ick=ic%4)
__global__ __launch_bounds__(256) void prep_w(const float* __restrict__ w,
                                              double* __restrict__ wT,
                                              int CIN, int n)
{
    int i = blockIdx.x * 256 + threadIdx.x;
    if (i >= n) return;
    int cin9 = CIN * 9;
    int oc   = i / cin9;
    int rem  = i - oc * cin9;
    int ic   = rem / 9;
    int dydx = rem - ic * 9;
    size_t dst = ((size_t)((oc >> 4) * (CIN >> 2) + (ic >> 2)) * 9 + dydx) * 64
               + (ic & 3) * 16 + (oc & 15);
    wT[dst] = (double)w[i];
}

// ---------------------------------------------------------------------------
// conv 3x3 pad 1 + bias + ReLU via v_mfma_f64_16x16x4_f64.
// block 256 = 4 waves; wave wv -> output row y0+wv; 5 px-tiles of 16 cols;
// 2 oc-blocks (32 oc) per block.  grid: (15 ytiles, COUT/32, G batches).
// Per 4-ic chunk: LDS holds act [4][6][82] + w [2][9][4][16], double-buffered;
// chunk k+1's global loads are issued before chunk k's MFMA phase.
// ---------------------------------------------------------------------------
template <int CIN, typename TIN, bool RELU>
__global__ __launch_bounds__(256) void conv3x3_mfma(
    const TIN* __restrict__ in,      // [G][CIN][60][80]
    const double* __restrict__ wT,   // transformed, see prep_w
    const double* __restrict__ bias, // [COUT]
    double* __restrict__ out)        // [G][COUT][60][80]
{
    const int COUT  = (CIN == 512) ? 256 : 128;
    const int NCH   = CIN / 4;
    const int ytile = blockIdx.x;          // 0..14 (4 rows each)
    const int ocp   = blockIdx.y;          // oc pair: covers oc [ocp*32, ocp*32+32)
    const int b     = blockIdx.z;
    const int tid   = threadIdx.x;
    const int wv    = tid >> 6;            // wave -> output row
    const int lane  = tid & 63;
    const int q     = lane >> 4;
    const int c     = lane & 15;
    const int y0    = ytile * 4;

    in  += (size_t)b * CIN  * PIX;
    out += (size_t)b * COUT * PIX;

    // ---- self-learn the D fragment map: code(l,i) = 16*X + Y ---------------
    int rowL[4], colL[4];
    {
        f64x4 pr = (f64x4){0.0, 0.0, 0.0, 0.0};
        double a1 = (lane < 16) ? (double)(16 * lane) : 0.0;
        double b1 = (lane < 16) ? 1.0 : 0.0;
        pr = __builtin_amdgcn_mfma_f64_16x16x4f64(a1, b1, pr, 0, 0, 0);
        double a2 = (lane < 16) ? 1.0 : 0.0;
        double b2 = (lane < 16) ? (double)lane : 0.0;
        pr = __builtin_amdgcn_mfma_f64_16x16x4f64(a2, b2, pr, 0, 0, 0);
#pragma unroll
        for (int i = 0; i < 4; ++i) {
            int code = (int)pr[i];
            rowL[i] = (code >> 4) & 15;
            colL[i] = code & 15;
        }
    }

    // LDS: double buffer of (act 1968 + w 1152) doubles = 2*3120*8 = 49,920 B
    __shared__ double smem[2][3120];

    const double* wbase = wT + (size_t)(ocp * 2) * NCH * 576;

    f64x4 acc[2][5];
#pragma unroll
    for (int o = 0; o < 2; ++o)
#pragma unroll
        for (int t = 0; t < 5; ++t) acc[o][t] = (f64x4){0.0, 0.0, 0.0, 0.0};

    const int bbase = q * 492 + wv * 82 + c;

    // register staging
    double ra[8];   // act: 1968 elems / 256 threads
    double rw[5];   // w:   1152 elems / 256 threads

    // ---- LOAD chunk -> regs (global); STORE regs -> LDS buffer -------------
#define LOAD_CHUNK(chk)                                                        \
    {                                                                          \
        const int ch = (chk);                                                  \
        _Pragma("unroll")                                                      \
        for (int j = 0; j < 8; ++j) {                                          \
            int i = tid + j * 256;                                             \
            if (i < 1968) {                                                    \
                int ick = i / 492;                                             \
                int rem = i - ick * 492;                                       \
                int ry  = rem / 82;                                            \
                int rx  = rem - ry * 82;                                       \
                int gy  = y0 - 1 + ry, gx = rx - 1;                            \
                double v = 0.0;                                                \
                if ((unsigned)gy < (unsigned)HC && (unsigned)gx < (unsigned)WC)\
                    v = (double)in[(size_t)(ch * 4 + ick) * PIX + gy * WC + gx];\
                ra[j] = v;                                                     \
            }                                                                  \
        }                                                                      \
        _Pragma("unroll")                                                      \
        for (int j = 0; j < 5; ++j) {                                          \
            int i = tid + j * 256;                                             \
            if (i < 1152) {                                                    \
                int o   = i / 576;                                             \
                int rem = i - o * 576;                                         \
                rw[j] = wbase[((size_t)o * NCH + ch) * 576 + rem];             \
            }                                                                  \
        }                                                                      \
    }

#define STORE_CHUNK(buf)                                                       \
    {                                                                          \
        double* dst = (buf);                                                   \
        _Pragma("unroll")                                                      \
        for (int j = 0; j < 8; ++j) {                                          \
            int i = tid + j * 256;                                             \
            if (i < 1968) dst[i] = ra[j];                                      \
        }                                                                      \
        _Pragma("unroll")                                                      \
        for (int j = 0; j < 5; ++j) {                                          \
            int i = tid + j * 256;                                             \
            if (i < 1152) dst[1968 + i] = rw[j];                               \
        }                                                                      \
    }

    LOAD_CHUNK(0);
    STORE_CHUNK(smem[0]);
    __syncthreads();

    for (int chk = 0; chk < NCH; ++chk) {
        const int cur = chk & 1;
        if (chk + 1 < NCH) LOAD_CHUNK(chk + 1);   // latency hides under MFMAs

        const double* act = smem[cur];
        const double* wl  = smem[cur] + 1968;

#pragma unroll
        for (int dy = 0; dy < 3; ++dy) {
#pragma unroll
            for (int dx = 0; dx < 3; ++dx) {
                const int dydx = dy * 3 + dx;
                double a0 = wl[dydx * 64 + lane];
                double a1 = wl[576 + dydx * 64 + lane];
#pragma unroll
                for (int t = 0; t < 5; ++t) {
                    double bv = act[bbase + dy * 82 + t * 16 + dx];
                    acc[0][t] = __builtin_amdgcn_mfma_f64_16x16x4f64(a0, bv, acc[0][t], 0, 0, 0);
                    acc[1][t] = __builtin_amdgcn_mfma_f64_16x16x4f64(a1, bv, acc[1][t], 0, 0, 0);
                }
            }
        }

        __syncthreads();
        if (chk + 1 < NCH) {
            STORE_CHUNK(smem[cur ^ 1]);
            __syncthreads();
        }
    }
#undef LOAD_CHUNK
#undef STORE_CHUNK

    // ---- epilogue: scatter via learned (X,Y), bias + ReLU ------------------
    const int y = y0 + wv;
#pragma unroll
    for (int o = 0; o < 2; ++o) {
#pragma unroll
        for (int t = 0; t < 5; ++t) {
#pragma unroll
            for (int i = 0; i < 4; ++i) {
                const int oc = ocp * 32 + o * 16 + rowL[i];
                double v = acc[o][t][i] + bias[oc];
                if (RELU) v = fmax(v, 0.0);
                out[(size_t)oc * PIX + y * WC + t * 16 + colL[i]] = v;
            }
        }
    }
}

// ---------------------------------------------------------------------------
// conv1x1 (128->65) + softmax(65)[:64] + pixel-unshuffle.  grid (19, G).
// ---------------------------------------------------------------------------
__global__ __launch_bounds__(256) void conv1x1_softmax_f64(
    const double* __restrict__ h2,   // [G][128][4800]
    const double* __restrict__ wg,   // [65][128]
    const double* __restrict__ bg,   // [65]
    double* __restrict__ S)          // [G][480][640]
{
    int p = blockIdx.x * 256 + threadIdx.x;
    if (p >= PIX) return;
    const int b = blockIdx.y;
    const double* h2p = h2 + (size_t)b * 128 * PIX + p;
    double* Sb = S + (size_t)b * IMG;

    double l[65];
#pragma unroll
    for (int o = 0; o < 65; ++o) l[o] = bg[o];

    for (int icc = 0; icc < 128; icc += 8) {
        double h[8];
#pragma unroll
        for (int k = 0; k < 8; ++k) h[k] = h2p[(size_t)(icc + k) * PIX];
#pragma unroll
        for (int o = 0; o < 65; ++o) {
            const double* wp = wg + o * 128 + icc;
            l[o] += h[0] * wp[0] + h[1] * wp[1] + h[2] * wp[2] + h[3] * wp[3]
                  + h[4] * wp[4] + h[5] * wp[5] + h[6] * wp[6] + h[7] * wp[7];
        }
    }

    double m = l[0];
#pragma unroll
    for (int o = 1; o < 65; ++o) m = fmax(m, l[o]);
    double s = 0.0;
#pragma unroll
    for (int o = 0; o < 65; ++o) { l[o] = exp(l[o] - m); s += l[o]; }
    double inv = 1.0 / s;

    int y = p / WC, x = p % WC;
#pragma unroll
    for (int cy = 0; cy < 8; ++cy)
#pragma unroll
        for (int cx2 = 0; cx2 < 8; ++cx2)
            Sb[(y * 8 + cy) * WF + x * 8 + cx2] = l[cy * 8 + cx2] * inv;
}

// ---------------------------------------------------------------------------
// NMS passes on f64 scores (equality decisions must be f64-exact).
// ---------------------------------------------------------------------------
__global__ __launch_bounds__(256) void hmax9_f64(const double* __restrict__ in,
                                                 double* __restrict__ out)
{
    int p = blockIdx.x * 256 + threadIdx.x;
    int x = p % WF;
    const double* row = in + (p - x);
    double m = row[x];
#pragma unroll
    for (int d = 1; d <= 4; ++d) {
        m = fmax(m, row[clampi(x - d, 0, WF - 1)]);
        m = fmax(m, row[clampi(x + d, 0, WF - 1)]);
    }
    out[p] = m;
}

__global__ __launch_bounds__(256) void vmax9_eq(const double* __restrict__ T,
                                                const double* __restrict__ S,
                                                unsigned char* __restrict__ M)
{
    int p = blockIdx.x * 256 + threadIdx.x;
    int y = (p % IMG) / WF;
    double m = T[p];
#pragma unroll
    for (int d = 1; d <= 4; ++d) {
        m = fmax(m, T[p + (clampi(y - d, 0, HF - 1) - y) * WF]);
        m = fmax(m, T[p + (clampi(y + d, 0, HF - 1) - y) * WF]);
    }
    M[p] = (S[p] == m) ? (unsigned char)1 : (unsigned char)0;
}

__global__ __launch_bounds__(256) void hor9_u8(const unsigned char* __restrict__ in,
                                               unsigned char* __restrict__ out)
{
    int p = blockIdx.x * 256 + threadIdx.x;
    int x = p % WF;
    const unsigned char* row = in + (p - x);
    unsigned char m = row[x];
#pragma unroll
    for (int d = 1; d <= 4; ++d) {
        m = m | row[clampi(x - d, 0, WF - 1)];
        m = m | row[clampi(x + d, 0, WF - 1)];
    }
    out[p] = m;
}

__global__ __launch_bounds__(256) void vor9_sup(const unsigned char* __restrict__ T8,
                                                unsigned char* __restrict__ SUP)
{
    int p = blockIdx.x * 256 + threadIdx.x;
    int y = (p % IMG) / WF;
    unsigned char m = T8[p];
#pragma unroll
    for (int d = 1; d <= 4; ++d) {
        m = m | T8[p + (clampi(y - d, 0, HF - 1) - y) * WF];
        m = m | T8[p + (clampi(y + d, 0, HF - 1) - y) * WF];
    }
    SUP[p] = m;
}

// horizontal max of (SUP ? 0 : S)
__global__ __launch_bounds__(256) void hmax9_supp(const double* __restrict__ S,
                                                  const unsigned char* __restrict__ SUP,
                                                  double* __restrict__ T)
{
    int p = blockIdx.x * 256 + threadIdx.x;
    int x = p % WF;
    int base = p - x;
    double m = SUP[p] ? 0.0 : S[p];
#pragma unroll
    for (int d = 1; d <= 4; ++d) {
        int i1 = base + clampi(x - d, 0, WF - 1);
        int i2 = base + clampi(x + d, 0, WF - 1);
        m = fmax(m, SUP[i1] ? 0.0 : S[i1]);
        m = fmax(m, SUP[i2] ? 0.0 : S[i2]);
    }
    T[p] = m;
}

__global__ __launch_bounds__(256) void vmax9_newmask(const double* __restrict__ T,
                                                     const double* __restrict__ S,
                                                     const unsigned char* __restrict__ SUP,
                                                     unsigned char* __restrict__ M)
{
    int p = blockIdx.x * 256 + threadIdx.x;
    int y = (p % IMG) / WF;
    double m = T[p];
#pragma unroll
    for (int d = 1; d <= 4; ++d) {
        m = fmax(m, T[p + (clampi(y - d, 0, HF - 1) - y) * WF]);
        m = fmax(m, T[p + (clampi(y + d, 0, HF - 1) - y) * WF]);
    }
    unsigned char nw = (!SUP[p] && S[p] == m) ? 1 : 0;
    M[p] = M[p] | nw;
}

__global__ __launch_bounds__(256) void final_mask(const double* __restrict__ S,
                                                  const unsigned char* __restrict__ M,
                                                  float* __restrict__ out)
{
    int p = blockIdx.x * 256 + threadIdx.x;
    out[p] = M[p] ? (float)S[p] : 0.f;
}

// ---------------------------------------------------------------------------
extern "C" void kernel_launch(void* const* d_in, const int* in_sizes, int n_in,
                              void* d_out, int out_size, void* d_ws, size_t ws_size,
                              hipStream_t stream)
{
    const float* x   = (const float*)d_in[0];
    const float* wPa = (const float*)d_in[1];
    const float* bPa = (const float*)d_in[2];
    const float* wPd = (const float*)d_in[3];
    const float* bPd = (const float*)d_in[4];
    const float* wPg = (const float*)d_in[5];
    const float* bPg = (const float*)d_in[6];
    float* out = (float*)d_out;

    char* ws = (char*)d_ws;
    // ---- persistent / NMS-phase layout -------------------------------------
    double*        S   = (double*)(ws);                        // 39,321,600
    double*        T   = (double*)(ws + 39321600);             // 39,321,600
    unsigned char* M   = (unsigned char*)(ws + 78643200);      //  4,915,200
    unsigned char* SUP = (unsigned char*)(ws + 83558400);      //  4,915,200
    unsigned char* T8  = (unsigned char*)(ws + 88473600);      //  4,915,200
    // ---- conv-phase overlay (inside T region, dead until NMS) --------------
    double* w1t = (double*)(ws + 39321600);   // 256*512*9*8 = 9,437,184 (transformed)
    double* w2t = (double*)(ws + 48758784);   // 128*256*9*8 = 2,359,296 (transformed)
    double* wgd = (double*)(ws + 51118080);   // 65*128*8    =    66,560
    double* b1d = (double*)(ws + 51184640);   // 2,048
    double* b2d = (double*)(ws + 51186688);   // 1,024
    double* bgd = (double*)(ws + 51187712);   // 1,024 (pad)
    char*   hbase = ws + 51188736;            // batch-group h1/h2 area

    // largest batch-group G with 51,188,736 + G*14,745,600 <= ws_size
    // (G=16 confirmed on hardware in rounds 3-6)
    int G = 1;
    for (int g = 16; g >= 1; g >>= 1) {
        if ((size_t)51188736 + (size_t)g * 14745600 <= ws_size) { G = g; break; }
    }

    // weights -> f64, mfma layout for 3x3 convs
    prep_w<<<(1179648 + 255) / 256, 256, 0, stream>>>(wPa, w1t, 512, 1179648);
    prep_w<<<(294912 + 255) / 256, 256, 0, stream>>>(wPd, w2t, 256, 294912);
    cvt_f32_f64<<<(8320 + 255) / 256, 256, 0, stream>>>(wPg, wgd, 8320);
    cvt_f32_f64<<<1, 256, 0, stream>>>(bPa, b1d, 256);
    cvt_f32_f64<<<1, 256, 0, stream>>>(bPd, b2d, 128);
    cvt_f32_f64<<<1, 256, 0, stream>>>(bPg, bgd, 65);

    for (int bg0 = 0; bg0 < B_; bg0 += G) {
        int Gc = (bg0 + G <= B_) ? G : (B_ - bg0);
        double* h1s = (double*)hbase;                              // Gc*256*4800 f64
        double* h2s = (double*)(hbase + (size_t)G * 9830400);      // Gc*128*4800 f64
        const float* xb = x + (size_t)bg0 * 512 * PIX;
        conv3x3_mfma<512, float, true><<<dim3(15, 8, Gc), 256, 0, stream>>>(xb, w1t, b1d, h1s);
        conv3x3_mfma<256, double, true><<<dim3(15, 4, Gc), 256, 0, stream>>>(h1s, w2t, b2d, h2s);
        conv1x1_softmax_f64<<<dim3(19, Gc), 256, 0, stream>>>(h2s, wgd, bgd, S + (size_t)bg0 * IMG);
    }

    const int NB = NPIX / 256;  // 19200
    hmax9_f64<<<NB, 256, 0, stream>>>(S, T);
    vmax9_eq<<<NB, 256, 0, stream>>>(T, S, M);
    for (int it = 0; it < 2; ++it) {
        hor9_u8<<<NB, 256, 0, stream>>>(M, T8);
        vor9_sup<<<NB, 256, 0, stream>>>(T8, SUP);
        hmax9_supp<<<NB, 256, 0, stream>>>(S, SUP, T);
        vmax9_newmask<<<NB, 256, 0, stream>>>(T, S, SUP, M);
    }
    final_mask<<<NB, 256, 0, stream>>>(S, M, out);
}

// Round 8
// 4782.331 us; speedup vs baseline: 2.7188x; 1.1149x over previous
//
#include <hip/hip_runtime.h>
#include <hip/hip_bf16.h>
#include <math.h>

// ---------------------------------------------------------------------------
// SuperPoint point head, f64 end-to-end (NMS exact-equality requires score
// ordering identical to the float64 numpy reference).
// Round 8: conv3x3 = oc16/block (r6 occupancy) + double-buffered LDS with ONE
// barrier per chunk (stores+load-issue overlap the MFMA phase) + precomputed
// staging offsets (no int division in the K-loop).
// D fragment map stays RUNTIME-LEARNED via 2 probe MFMAs (round-6 win).
// ---------------------------------------------------------------------------

#define B_      16
#define HC      60
#define WC      80
#define PIX     (HC * WC)          // 4800
#define HF      480
#define WF      640
#define IMG     (HF * WF)          // 307200
#define NPIX    (B_ * IMG)         // 4915200

typedef double f64x4 __attribute__((ext_vector_type(4)));

__device__ __forceinline__ int clampi(int v, int lo, int hi) {
    return v < lo ? lo : (v > hi ? hi : v);
}

// ---------------------------------------------------------------------------
__global__ __launch_bounds__(256) void cvt_f32_f64(const float* __restrict__ s,
                                                   double* __restrict__ d, int n)
{
    int i = blockIdx.x * 256 + threadIdx.x;
    if (i < n) d[i] = (double)s[i];
}

// Weight pre-transform: w[oc][ic][3][3] f32 -> wT f64 laid out as
// [ocb][chk][dydx][ick][ocl]  (ocb=oc/16, ocl=oc%16, chk=ic/4, ick=ic%4)
__global__ __launch_bounds__(256) void prep_w(const float* __restrict__ w,
                                              double* __restrict__ wT,
                                              int CIN, int n)
{
    int i = blockIdx.x * 256 + threadIdx.x;
    if (i >= n) return;
    int cin9 = CIN * 9;
    int oc   = i / cin9;
    int rem  = i - oc * cin9;
    int ic   = rem / 9;
    int dydx = rem - ic * 9;
    size_t dst = ((size_t)((oc >> 4) * (CIN >> 2) + (ic >> 2)) * 9 + dydx) * 64
               + (ic & 3) * 16 + (oc & 15);
    wT[dst] = (double)w[i];
}

// ---------------------------------------------------------------------------
// conv 3x3 pad 1 + bias + ReLU via v_mfma_f64_16x16x4_f64.
// block 256 = 4 waves; wave wv -> output row y0+wv; 5 px-tiles of 16 cols;
// 16 oc per block.  grid: (15 ytiles, COUT/16, G batches).
// Per 4-ic chunk (one barrier each):
//   ds_write chunk k+1 -> buf^1   (overlaps MFMA issue)
//   issue global loads k+2 -> regs (completes under the 2880cy MFMA phase)
//   45 MFMAs on buf; __syncthreads()
// ---------------------------------------------------------------------------
template <int CIN, typename TIN, bool RELU>
__global__ __launch_bounds__(256, 4) void conv3x3_mfma(
    const TIN* __restrict__ in,      // [G][CIN][60][80]
    const double* __restrict__ wT,   // transformed, see prep_w
    const double* __restrict__ bias, // [COUT]
    double* __restrict__ out)        // [G][COUT][60][80]
{
    const int COUT  = (CIN == 512) ? 256 : 128;
    const int NCH   = CIN / 4;
    const int ytile = blockIdx.x;          // 0..14 (4 rows each)
    const int ocb   = blockIdx.y;
    const int oc0   = ocb * 16;
    const int b     = blockIdx.z;
    const int tid   = threadIdx.x;
    const int wv    = tid >> 6;            // wave -> output row
    const int lane  = tid & 63;
    const int q     = lane >> 4;
    const int c     = lane & 15;
    const int y0    = ytile * 4;

    in  += (size_t)b * CIN  * PIX;
    out += (size_t)b * COUT * PIX;

    // ---- self-learn the D fragment map: code(l,i) = 16*X + Y ---------------
    int rowL[4], colL[4];
    {
        f64x4 pr = (f64x4){0.0, 0.0, 0.0, 0.0};
        double a1 = (lane < 16) ? (double)(16 * lane) : 0.0;
        double b1 = (lane < 16) ? 1.0 : 0.0;
        pr = __builtin_amdgcn_mfma_f64_16x16x4f64(a1, b1, pr, 0, 0, 0);
        double a2 = (lane < 16) ? 1.0 : 0.0;
        double b2 = (lane < 16) ? (double)lane : 0.0;
        pr = __builtin_amdgcn_mfma_f64_16x16x4f64(a2, b2, pr, 0, 0, 0);
#pragma unroll
        for (int i = 0; i < 4; ++i) {
            int code = (int)pr[i];
            rowL[i] = (code >> 4) & 15;
            colL[i] = code & 15;
        }
    }

    // double-buffered LDS: 2 x (act 1968 + w 576) = 2*2544*8 = 40,704 B
    __shared__ double smem[2][2544];

    const double* wchunk = wT + (size_t)ocb * NCH * 576;

    f64x4 acc[5];
#pragma unroll
    for (int t = 0; t < 5; ++t) acc[t] = (f64x4){0.0, 0.0, 0.0, 0.0};

    const int bbase = q * 492 + wv * 82 + c;

    // ---- precompute staging offsets once (no divisions in the K-loop) ------
    // act element i (0..1967): ick=i/492, rem=i-ick*492, ry=rem/82, rx=rem-ry*82
    int aOff[8];
#pragma unroll
    for (int j = 0; j < 8; ++j) {
        int i   = tid + j * 256;
        int ick = i / 492;
        int rem = i - ick * 492;
        int ry  = rem / 82;
        int rx  = rem - ry * 82;
        int gy  = y0 - 1 + ry, gx = rx - 1;
        bool ok = (i < 1968) && ((unsigned)gy < (unsigned)HC) && ((unsigned)gx < (unsigned)WC);
        aOff[j] = ok ? (ick * PIX + gy * WC + gx) : -1;
    }

    double ra[8];
    double rw0, rw1, rw2;

#define LOADC(ch)                                                              \
    {                                                                          \
        const int gbase = (ch) * 4 * PIX;                                      \
        _Pragma("unroll")                                                      \
        for (int j = 0; j < 8; ++j)                                            \
            ra[j] = (aOff[j] >= 0) ? (double)in[gbase + aOff[j]] : 0.0;        \
        const double* wp = wchunk + (size_t)(ch) * 576;                        \
        rw0 = wp[tid];                                                         \
        rw1 = wp[256 + tid];                                                   \
        rw2 = (tid < 64) ? wp[512 + tid] : 0.0;                                \
    }

#define STOREC(sel)                                                            \
    {                                                                          \
        double* dst = smem[sel];                                               \
        _Pragma("unroll")                                                      \
        for (int j = 0; j < 7; ++j) dst[tid + j * 256] = ra[j];                \
        if (tid < 176) dst[tid + 1792] = ra[7];                                \
        dst[1968 + tid] = rw0;                                                 \
        dst[1968 + 256 + tid] = rw1;                                           \
        if (tid < 64) dst[1968 + 512 + tid] = rw2;                             \
    }

    LOADC(0);
    STOREC(0);
    LOADC(1);                      // chunk 1 -> regs
    __syncthreads();

    for (int chk = 0; chk < NCH; ++chk) {
        const int cur = chk & 1;
        if (chk + 1 < NCH) STOREC(cur ^ 1);   // regs hold chunk chk+1
        if (chk + 2 < NCH) LOADC(chk + 2);    // completes under MFMA phase

        const double* act = smem[cur];
        const double* wl  = smem[cur] + 1968;
#pragma unroll
        for (int dy = 0; dy < 3; ++dy) {
#pragma unroll
            for (int dx = 0; dx < 3; ++dx) {
                double a = wl[(dy * 3 + dx) * 64 + lane];
#pragma unroll
                for (int t = 0; t < 5; ++t) {
                    double bv = act[bbase + dy * 82 + t * 16 + dx];
                    acc[t] = __builtin_amdgcn_mfma_f64_16x16x4f64(a, bv, acc[t], 0, 0, 0);
                }
            }
        }
        if (chk + 1 < NCH) __syncthreads();
    }
#undef LOADC
#undef STOREC

    // ---- epilogue: scatter via learned (X,Y), bias + ReLU ------------------
    const int y = y0 + wv;
#pragma unroll
    for (int t = 0; t < 5; ++t) {
#pragma unroll
        for (int i = 0; i < 4; ++i) {
            const int oc = oc0 + rowL[i];
            double v = acc[t][i] + bias[oc];
            if (RELU) v = fmax(v, 0.0);
            out[(size_t)oc * PIX + y * WC + t * 16 + colL[i]] = v;
        }
    }
}

// ---------------------------------------------------------------------------
// conv1x1 (128->65) + softmax(65)[:64] + pixel-unshuffle.  grid (19, G).
// ---------------------------------------------------------------------------
__global__ __launch_bounds__(256) void conv1x1_softmax_f64(
    const double* __restrict__ h2,   // [G][128][4800]
    const double* __restrict__ wg,   // [65][128]
    const double* __restrict__ bg,   // [65]
    double* __restrict__ S)          // [G][480][640]
{
    int p = blockIdx.x * 256 + threadIdx.x;
    if (p >= PIX) return;
    const int b = blockIdx.y;
    const double* h2p = h2 + (size_t)b * 128 * PIX + p;
    double* Sb = S + (size_t)b * IMG;

    double l[65];
#pragma unroll
    for (int o = 0; o < 65; ++o) l[o] = bg[o];

    for (int icc = 0; icc < 128; icc += 8) {
        double h[8];
#pragma unroll
        for (int k = 0; k < 8; ++k) h[k] = h2p[(size_t)(icc + k) * PIX];
#pragma unroll
        for (int o = 0; o < 65; ++o) {
            const double* wp = wg + o * 128 + icc;
            l[o] += h[0] * wp[0] + h[1] * wp[1] + h[2] * wp[2] + h[3] * wp[3]
                  + h[4] * wp[4] + h[5] * wp[5] + h[6] * wp[6] + h[7] * wp[7];
        }
    }

    double m = l[0];
#pragma unroll
    for (int o = 1; o < 65; ++o) m = fmax(m, l[o]);
    double s = 0.0;
#pragma unroll
    for (int o = 0; o < 65; ++o) { l[o] = exp(l[o] - m); s += l[o]; }
    double inv = 1.0 / s;

    int y = p / WC, x = p % WC;
#pragma unroll
    for (int cy = 0; cy < 8; ++cy)
#pragma unroll
        for (int cx2 = 0; cx2 < 8; ++cx2)
            Sb[(y * 8 + cy) * WF + x * 8 + cx2] = l[cy * 8 + cx2] * inv;
}

// ---------------------------------------------------------------------------
// NMS passes on f64 scores (equality decisions must be f64-exact).
// ---------------------------------------------------------------------------
__global__ __launch_bounds__(256) void hmax9_f64(const double* __restrict__ in,
                                                 double* __restrict__ out)
{
    int p = blockIdx.x * 256 + threadIdx.x;
    int x = p % WF;
    const double* row = in + (p - x);
    double m = row[x];
#pragma unroll
    for (int d = 1; d <= 4; ++d) {
        m = fmax(m, row[clampi(x - d, 0, WF - 1)]);
        m = fmax(m, row[clampi(x + d, 0, WF - 1)]);
    }
    out[p] = m;
}

__global__ __launch_bounds__(256) void vmax9_eq(const double* __restrict__ T,
                                                const double* __restrict__ S,
                                                unsigned char* __restrict__ M)
{
    int p = blockIdx.x * 256 + threadIdx.x;
    int y = (p % IMG) / WF;
    double m = T[p];
#pragma unroll
    for (int d = 1; d <= 4; ++d) {
        m = fmax(m, T[p + (clampi(y - d, 0, HF - 1) - y) * WF]);
        m = fmax(m, T[p + (clampi(y + d, 0, HF - 1) - y) * WF]);
    }
    M[p] = (S[p] == m) ? (unsigned char)1 : (unsigned char)0;
}

__global__ __launch_bounds__(256) void hor9_u8(const unsigned char* __restrict__ in,
                                               unsigned char* __restrict__ out)
{
    int p = blockIdx.x * 256 + threadIdx.x;
    int x = p % WF;
    const unsigned char* row = in + (p - x);
    unsigned char m = row[x];
#pragma unroll
    for (int d = 1; d <= 4; ++d) {
        m = m | row[clampi(x - d, 0, WF - 1)];
        m = m | row[clampi(x + d, 0, WF - 1)];
    }
    out[p] = m;
}

__global__ __launch_bounds__(256) void vor9_sup(const unsigned char* __restrict__ T8,
                                                unsigned char* __restrict__ SUP)
{
    int p = blockIdx.x * 256 + threadIdx.x;
    int y = (p % IMG) / WF;
    unsigned char m = T8[p];
#pragma unroll
    for (int d = 1; d <= 4; ++d) {
        m = m | T8[p + (clampi(y - d, 0, HF - 1) - y) * WF];
        m = m | T8[p + (clampi(y + d, 0, HF - 1) - y) * WF];
    }
    SUP[p] = m;
}

// horizontal max of (SUP ? 0 : S)
__global__ __launch_bounds__(256) void hmax9_supp(const double* __restrict__ S,
                                                  const unsigned char* __restrict__ SUP,
                                                  double* __restrict__ T)
{
    int p = blockIdx.x * 256 + threadIdx.x;
    int x = p % WF;
    int base = p - x;
    double m = SUP[p] ? 0.0 : S[p];
#pragma unroll
    for (int d = 1; d <= 4; ++d) {
        int i1 = base + clampi(x - d, 0, WF - 1);
        int i2 = base + clampi(x + d, 0, WF - 1);
        m = fmax(m, SUP[i1] ? 0.0 : S[i1]);
        m = fmax(m, SUP[i2] ? 0.0 : S[i2]);
    }
    T[p] = m;
}

__global__ __launch_bounds__(256) void vmax9_newmask(const double* __restrict__ T,
                                                     const double* __restrict__ S,
                                                     const unsigned char* __restrict__ SUP,
                                                     unsigned char* __restrict__ M)
{
    int p = blockIdx.x * 256 + threadIdx.x;
    int y = (p % IMG) / WF;
    double m = T[p];
#pragma unroll
    for (int d = 1; d <= 4; ++d) {
        m = fmax(m, T[p + (clampi(y - d, 0, HF - 1) - y) * WF]);
        m = fmax(m, T[p + (clampi(y + d, 0, HF - 1) - y) * WF]);
    }
    unsigned char nw = (!SUP[p] && S[p] == m) ? 1 : 0;
    M[p] = M[p] | nw;
}

__global__ __launch_bounds__(256) void final_mask(const double* __restrict__ S,
                                                  const unsigned char* __restrict__ M,
                                                  float* __restrict__ out)
{
    int p = blockIdx.x * 256 + threadIdx.x;
    out[p] = M[p] ? (float)S[p] : 0.f;
}

// ---------------------------------------------------------------------------
extern "C" void kernel_launch(void* const* d_in, const int* in_sizes, int n_in,
                              void* d_out, int out_size, void* d_ws, size_t ws_size,
                              hipStream_t stream)
{
    const float* x   = (const float*)d_in[0];
    const float* wPa = (const float*)d_in[1];
    const float* bPa = (const float*)d_in[2];
    const float* wPd = (const float*)d_in[3];
    const float* bPd = (const float*)d_in[4];
    const float* wPg = (const float*)d_in[5];
    const float* bPg = (const float*)d_in[6];
    float* out = (float*)d_out;

    char* ws = (char*)d_ws;
    // ---- persistent / NMS-phase layout -------------------------------------
    double*        S   = (double*)(ws);                        // 39,321,600
    double*        T   = (double*)(ws + 39321600);             // 39,321,600
    unsigned char* M   = (unsigned char*)(ws + 78643200);      //  4,915,200
    unsigned char* SUP = (unsigned char*)(ws + 83558400);      //  4,915,200
    unsigned char* T8  = (unsigned char*)(ws + 88473600);      //  4,915,200
    // ---- conv-phase overlay (inside T region, dead until NMS) --------------
    double* w1t = (double*)(ws + 39321600);   // 256*512*9*8 = 9,437,184 (transformed)
    double* w2t = (double*)(ws + 48758784);   // 128*256*9*8 = 2,359,296 (transformed)
    double* wgd = (double*)(ws + 51118080);   // 65*128*8    =    66,560
    double* b1d = (double*)(ws + 51184640);   // 2,048
    double* b2d = (double*)(ws + 51186688);   // 1,024
    double* bgd = (double*)(ws + 51187712);   // 1,024 (pad)
    char*   hbase = ws + 51188736;            // batch-group h1/h2 area

    // largest batch-group G with 51,188,736 + G*14,745,600 <= ws_size
    // (G=16 confirmed on hardware in rounds 3-7)
    int G = 1;
    for (int g = 16; g >= 1; g >>= 1) {
        if ((size_t)51188736 + (size_t)g * 14745600 <= ws_size) { G = g; break; }
    }

    // weights -> f64, mfma layout for 3x3 convs
    prep_w<<<(1179648 + 255) / 256, 256, 0, stream>>>(wPa, w1t, 512, 1179648);
    prep_w<<<(294912 + 255) / 256, 256, 0, stream>>>(wPd, w2t, 256, 294912);
    cvt_f32_f64<<<(8320 + 255) / 256, 256, 0, stream>>>(wPg, wgd, 8320);
    cvt_f32_f64<<<1, 256, 0, stream>>>(bPa, b1d, 256);
    cvt_f32_f64<<<1, 256, 0, stream>>>(bPd, b2d, 128);
    cvt_f32_f64<<<1, 256, 0, stream>>>(bPg, bgd, 65);

    for (int bg0 = 0; bg0 < B_; bg0 += G) {
        int Gc = (bg0 + G <= B_) ? G : (B_ - bg0);
        double* h1s = (double*)hbase;                              // Gc*256*4800 f64
        double* h2s = (double*)(hbase + (size_t)G * 9830400);      // Gc*128*4800 f64
        const float* xb = x + (size_t)bg0 * 512 * PIX;
        conv3x3_mfma<512, float, true><<<dim3(15, 16, Gc), 256, 0, stream>>>(xb, w1t, b1d, h1s);
        conv3x3_mfma<256, double, true><<<dim3(15, 8, Gc), 256, 0, stream>>>(h1s, w2t, b2d, h2s);
        conv1x1_softmax_f64<<<dim3(19, Gc), 256, 0, stream>>>(h2s, wgd, bgd, S + (size_t)bg0 * IMG);
    }

    const int NB = NPIX / 256;  // 19200
    hmax9_f64<<<NB, 256, 0, stream>>>(S, T);
    vmax9_eq<<<NB, 256, 0, stream>>>(T, S, M);
    for (int it = 0; it < 2; ++it) {
        hor9_u8<<<NB, 256, 0, stream>>>(M, T8);
        vor9_sup<<<NB, 256, 0, stream>>>(T8, SUP);
        hmax9_supp<<<NB, 256, 0, stream>>>(S, SUP, T);
        vmax9_newmask<<<NB, 256, 0, stream>>>(T, S, SUP, M);
    }
    final_mask<<<NB, 256, 0, stream>>>(S, M, out);
}

// Round 9
// 4471.353 us; speedup vs baseline: 2.9079x; 1.0695x over previous
//
#include <hip/hip_runtime.h>
#include <hip/hip_bf16.h>
#include <math.h>

// ---------------------------------------------------------------------------
// SuperPoint point head, f64 end-to-end (NMS exact-equality requires score
// ordering identical to the float64 numpy reference).
// Round 9: conv3x3 restructured around the LDS-pipe bottleneck found in r8:
//   - weights (A-operand) load straight from global (L2-hot, coalesced 512B)
//   - 2 oc-blocks per wave: 45 B ds_reads feed 90 MFMAs (reads/MFMA halved)
//   - block = 2 rows x 64 oc, act tile [4ic][4rows][82] dbuf = 21KB LDS
// Accumulation order per output unchanged -> bit-identical scores.
// D fragment map stays RUNTIME-LEARNED via 2 probe MFMAs (round-6 win).
// ---------------------------------------------------------------------------

#define B_      16
#define HC      60
#define WC      80
#define PIX     (HC * WC)          // 4800
#define HF      480
#define WF      640
#define IMG     (HF * WF)          // 307200
#define NPIX    (B_ * IMG)         // 4915200

typedef double f64x4 __attribute__((ext_vector_type(4)));

__device__ __forceinline__ int clampi(int v, int lo, int hi) {
    return v < lo ? lo : (v > hi ? hi : v);
}

// ---------------------------------------------------------------------------
__global__ __launch_bounds__(256) void cvt_f32_f64(const float* __restrict__ s,
                                                   double* __restrict__ d, int n)
{
    int i = blockIdx.x * 256 + threadIdx.x;
    if (i < n) d[i] = (double)s[i];
}

// Weight pre-transform: w[oc][ic][3][3] f32 -> wT f64 laid out as
// [ocb][chk][dydx][ick][ocl]  (ocb=oc/16, ocl=oc%16, chk=ic/4, ick=ic%4)
__global__ __launch_bounds__(256) void prep_w(const float* __restrict__ w,
                                              double* __restrict__ wT,
                                              int CIN, int n)
{
    int i = blockIdx.x * 256 + threadIdx.x;
    if (i >= n) return;
    int cin9 = CIN * 9;
    int oc   = i / cin9;
    int rem  = i - oc * cin9;
    int ic   = rem / 9;
    int dydx = rem - ic * 9;
    size_t dst = ((size_t)((oc >> 4) * (CIN >> 2) + (ic >> 2)) * 9 + dydx) * 64
               + (ic & 3) * 16 + (oc & 15);
    wT[dst] = (double)w[i];
}

// ---------------------------------------------------------------------------
// conv 3x3 pad 1 + bias + ReLU via v_mfma_f64_16x16x4_f64.
// block 256 = 4 waves = (2 output rows) x (2 ocb-pairs); 64 oc per block.
// wave wv: row = y0 + (wv&1), oc-blocks {base, base+1} with base=ocq*4+(wv>>1)*2.
// grid: (30 ytiles, COUT/64, G batches).
// Per 4-ic chunk (one barrier): ds_write next act; issue act loads k+2;
// A-operands from GLOBAL (L2-hot) inside the unrolled dydx loop; 90 MFMAs.
// ---------------------------------------------------------------------------
template <int CIN, typename TIN, bool RELU>
__global__ __launch_bounds__(256, 3) void conv3x3_mfma(
    const TIN* __restrict__ in,      // [G][CIN][60][80]
    const double* __restrict__ wT,   // transformed, see prep_w
    const double* __restrict__ bias, // [COUT]
    double* __restrict__ out)        // [G][COUT][60][80]
{
    const int COUT  = (CIN == 512) ? 256 : 128;
    const int NCH   = CIN / 4;
    const int ytile = blockIdx.x;          // 0..29 (2 rows each)
    const int ocq   = blockIdx.y;          // 64-oc group
    const int b     = blockIdx.z;
    const int tid   = threadIdx.x;
    const int wv    = tid >> 6;
    const int lane  = tid & 63;
    const int q     = lane >> 4;
    const int c     = lane & 15;
    const int wr    = wv & 1;              // wave's output row (0/1)
    const int wo    = wv >> 1;             // wave's ocb-pair (0/1)
    const int y0    = ytile * 2;
    const int y     = y0 + wr;

    in  += (size_t)b * CIN  * PIX;
    out += (size_t)b * COUT * PIX;

    // ---- self-learn the D fragment map: code(l,i) = 16*X + Y ---------------
    int rowL[4], colL[4];
    {
        f64x4 pr = (f64x4){0.0, 0.0, 0.0, 0.0};
        double a1 = (lane < 16) ? (double)(16 * lane) : 0.0;
        double b1 = (lane < 16) ? 1.0 : 0.0;
        pr = __builtin_amdgcn_mfma_f64_16x16x4f64(a1, b1, pr, 0, 0, 0);
        double a2 = (lane < 16) ? 1.0 : 0.0;
        double b2 = (lane < 16) ? (double)lane : 0.0;
        pr = __builtin_amdgcn_mfma_f64_16x16x4f64(a2, b2, pr, 0, 0, 0);
#pragma unroll
        for (int i = 0; i < 4; ++i) {
            int code = (int)pr[i];
            rowL[i] = (code >> 4) & 15;
            colL[i] = code & 15;
        }
    }

    // act double buffer: [2][4ic][4rows][82] = 2*1312 doubles = 20,992 B
    __shared__ double smem[2][1312];

    // this wave's two weight streams (global; shared by 480 blocks -> L2-hot)
    const int ocb0 = ocq * 4 + wo * 2;
    const double* wA = wT + (size_t)ocb0 * NCH * 576;
    const double* wB = wT + (size_t)(ocb0 + 1) * NCH * 576;

    f64x4 acc[2][5];
#pragma unroll
    for (int o = 0; o < 2; ++o)
#pragma unroll
        for (int t = 0; t < 5; ++t) acc[o][t] = (f64x4){0.0, 0.0, 0.0, 0.0};

    const int bbase = q * 328 + wr * 82 + c;

    // ---- precompute act staging offsets (1312 elems, 6 per thread) ---------
    int aOff[6];
#pragma unroll
    for (int j = 0; j < 6; ++j) {
        int i   = tid + j * 256;
        int ick = i / 328;
        int rem = i - ick * 328;
        int ry  = rem / 82;
        int rx  = rem - ry * 82;
        int gy  = y0 - 1 + ry, gx = rx - 1;
        bool ok = (i < 1312) && ((unsigned)gy < (unsigned)HC) && ((unsigned)gx < (unsigned)WC);
        aOff[j] = ok ? (ick * PIX + gy * WC + gx) : -1;
    }

    double ra[6];

#define LOADC(ch)                                                              \
    {                                                                          \
        const int gbase = (ch) * 4 * PIX;                                      \
        _Pragma("unroll")                                                      \
        for (int j = 0; j < 6; ++j)                                            \
            ra[j] = (aOff[j] >= 0) ? (double)in[gbase + aOff[j]] : 0.0;        \
    }

#define STOREC(sel)                                                            \
    {                                                                          \
        double* dst = smem[sel];                                               \
        _Pragma("unroll")                                                      \
        for (int j = 0; j < 5; ++j) dst[tid + j * 256] = ra[j];                \
        if (tid < 32) dst[1280 + tid] = ra[5];                                 \
    }

    LOADC(0);
    STOREC(0);
    LOADC(1);
    __syncthreads();

    for (int chk = 0; chk < NCH; ++chk) {
        const int cur = chk & 1;
        if (chk + 1 < NCH) STOREC(cur ^ 1);   // regs hold chunk chk+1
        if (chk + 2 < NCH) LOADC(chk + 2);    // completes under MFMA phase

        const double* wa  = wA + (size_t)chk * 576;
        const double* wb  = wB + (size_t)chk * 576;
        const double* act = smem[cur];

#pragma unroll
        for (int dy = 0; dy < 3; ++dy) {
#pragma unroll
            for (int dx = 0; dx < 3; ++dx) {
                const int d = dy * 3 + dx;
                double a0 = wa[d * 64 + lane];
                double a1 = wb[d * 64 + lane];
#pragma unroll
                for (int t = 0; t < 5; ++t) {
                    double bv = act[bbase + dy * 82 + t * 16 + dx];
                    acc[0][t] = __builtin_amdgcn_mfma_f64_16x16x4f64(a0, bv, acc[0][t], 0, 0, 0);
                    acc[1][t] = __builtin_amdgcn_mfma_f64_16x16x4f64(a1, bv, acc[1][t], 0, 0, 0);
                }
            }
        }
        if (chk + 1 < NCH) __syncthreads();
    }
#undef LOADC
#undef STOREC

    // ---- epilogue: scatter via learned (X,Y), bias + ReLU ------------------
#pragma unroll
    for (int o = 0; o < 2; ++o) {
#pragma unroll
        for (int t = 0; t < 5; ++t) {
#pragma unroll
            for (int i = 0; i < 4; ++i) {
                const int oc = (ocb0 + o) * 16 + rowL[i];
                double v = acc[o][t][i] + bias[oc];
                if (RELU) v = fmax(v, 0.0);
                out[(size_t)oc * PIX + y * WC + t * 16 + colL[i]] = v;
            }
        }
    }
}

// ---------------------------------------------------------------------------
// conv1x1 (128->65) + softmax(65)[:64] + pixel-unshuffle.  grid (19, G).
// ---------------------------------------------------------------------------
__global__ __launch_bounds__(256) void conv1x1_softmax_f64(
    const double* __restrict__ h2,   // [G][128][4800]
    const double* __restrict__ wg,   // [65][128]
    const double* __restrict__ bg,   // [65]
    double* __restrict__ S)          // [G][480][640]
{
    int p = blockIdx.x * 256 + threadIdx.x;
    if (p >= PIX) return;
    const int b = blockIdx.y;
    const double* h2p = h2 + (size_t)b * 128 * PIX + p;
    double* Sb = S + (size_t)b * IMG;

    double l[65];
#pragma unroll
    for (int o = 0; o < 65; ++o) l[o] = bg[o];

    for (int icc = 0; icc < 128; icc += 8) {
        double h[8];
#pragma unroll
        for (int k = 0; k < 8; ++k) h[k] = h2p[(size_t)(icc + k) * PIX];
#pragma unroll
        for (int o = 0; o < 65; ++o) {
            const double* wp = wg + o * 128 + icc;
            l[o] += h[0] * wp[0] + h[1] * wp[1] + h[2] * wp[2] + h[3] * wp[3]
                  + h[4] * wp[4] + h[5] * wp[5] + h[6] * wp[6] + h[7] * wp[7];
        }
    }

    double m = l[0];
#pragma unroll
    for (int o = 1; o < 65; ++o) m = fmax(m, l[o]);
    double s = 0.0;
#pragma unroll
    for (int o = 0; o < 65; ++o) { l[o] = exp(l[o] - m); s += l[o]; }
    double inv = 1.0 / s;

    int y = p / WC, x = p % WC;
#pragma unroll
    for (int cy = 0; cy < 8; ++cy)
#pragma unroll
        for (int cx2 = 0; cx2 < 8; ++cx2)
            Sb[(y * 8 + cy) * WF + x * 8 + cx2] = l[cy * 8 + cx2] * inv;
}

// ---------------------------------------------------------------------------
// NMS passes on f64 scores (equality decisions must be f64-exact).
// ---------------------------------------------------------------------------
__global__ __launch_bounds__(256) void hmax9_f64(const double* __restrict__ in,
                                                 double* __restrict__ out)
{
    int p = blockIdx.x * 256 + threadIdx.x;
    int x = p % WF;
    const double* row = in + (p - x);
    double m = row[x];
#pragma unroll
    for (int d = 1; d <= 4; ++d) {
        m = fmax(m, row[clampi(x - d, 0, WF - 1)]);
        m = fmax(m, row[clampi(x + d, 0, WF - 1)]);
    }
    out[p] = m;
}

__global__ __launch_bounds__(256) void vmax9_eq(const double* __restrict__ T,
                                                const double* __restrict__ S,
                                                unsigned char* __restrict__ M)
{
    int p = blockIdx.x * 256 + threadIdx.x;
    int y = (p % IMG) / WF;
    double m = T[p];
#pragma unroll
    for (int d = 1; d <= 4; ++d) {
        m = fmax(m, T[p + (clampi(y - d, 0, HF - 1) - y) * WF]);
        m = fmax(m, T[p + (clampi(y + d, 0, HF - 1) - y) * WF]);
    }
    M[p] = (S[p] == m) ? (unsigned char)1 : (unsigned char)0;
}

__global__ __launch_bounds__(256) void hor9_u8(const unsigned char* __restrict__ in,
                                               unsigned char* __restrict__ out)
{
    int p = blockIdx.x * 256 + threadIdx.x;
    int x = p % WF;
    const unsigned char* row = in + (p - x);
    unsigned char m = row[x];
#pragma unroll
    for (int d = 1; d <= 4; ++d) {
        m = m | row[clampi(x - d, 0, WF - 1)];
        m = m | row[clampi(x + d, 0, WF - 1)];
    }
    out[p] = m;
}

__global__ __launch_bounds__(256) void vor9_sup(const unsigned char* __restrict__ T8,
                                                unsigned char* __restrict__ SUP)
{
    int p = blockIdx.x * 256 + threadIdx.x;
    int y = (p % IMG) / WF;
    unsigned char m = T8[p];
#pragma unroll
    for (int d = 1; d <= 4; ++d) {
        m = m | T8[p + (clampi(y - d, 0, HF - 1) - y) * WF];
        m = m | T8[p + (clampi(y + d, 0, HF - 1) - y) * WF];
    }
    SUP[p] = m;
}

// horizontal max of (SUP ? 0 : S)
__global__ __launch_bounds__(256) void hmax9_supp(const double* __restrict__ S,
                                                  const unsigned char* __restrict__ SUP,
                                                  double* __restrict__ T)
{
    int p = blockIdx.x * 256 + threadIdx.x;
    int x = p % WF;
    int base = p - x;
    double m = SUP[p] ? 0.0 : S[p];
#pragma unroll
    for (int d = 1; d <= 4; ++d) {
        int i1 = base + clampi(x - d, 0, WF - 1);
        int i2 = base + clampi(x + d, 0, WF - 1);
        m = fmax(m, SUP[i1] ? 0.0 : S[i1]);
        m = fmax(m, SUP[i2] ? 0.0 : S[i2]);
    }
    T[p] = m;
}

__global__ __launch_bounds__(256) void vmax9_newmask(const double* __restrict__ T,
                                                     const double* __restrict__ S,
                                                     const unsigned char* __restrict__ SUP,
                                                     unsigned char* __restrict__ M)
{
    int p = blockIdx.x * 256 + threadIdx.x;
    int y = (p % IMG) / WF;
    double m = T[p];
#pragma unroll
    for (int d = 1; d <= 4; ++d) {
        m = fmax(m, T[p + (clampi(y - d, 0, HF - 1) - y) * WF]);
        m = fmax(m, T[p + (clampi(y + d, 0, HF - 1) - y) * WF]);
    }
    unsigned char nw = (!SUP[p] && S[p] == m) ? 1 : 0;
    M[p] = M[p] | nw;
}

__global__ __launch_bounds__(256) void final_mask(const double* __restrict__ S,
                                                  const unsigned char* __restrict__ M,
                                                  float* __restrict__ out)
{
    int p = blockIdx.x * 256 + threadIdx.x;
    out[p] = M[p] ? (float)S[p] : 0.f;
}

// ---------------------------------------------------------------------------
extern "C" void kernel_launch(void* const* d_in, const int* in_sizes, int n_in,
                              void* d_out, int out_size, void* d_ws, size_t ws_size,
                              hipStream_t stream)
{
    const float* x   = (const float*)d_in[0];
    const float* wPa = (const float*)d_in[1];
    const float* bPa = (const float*)d_in[2];
    const float* wPd = (const float*)d_in[3];
    const float* bPd = (const float*)d_in[4];
    const float* wPg = (const float*)d_in[5];
    const float* bPg = (const float*)d_in[6];
    float* out = (float*)d_out;

    char* ws = (char*)d_ws;
    // ---- persistent / NMS-phase layout -------------------------------------
    double*        S   = (double*)(ws);                        // 39,321,600
    double*        T   = (double*)(ws + 39321600);             // 39,321,600
    unsigned char* M   = (unsigned char*)(ws + 78643200);      //  4,915,200
    unsigned char* SUP = (unsigned char*)(ws + 83558400);      //  4,915,200
    unsigned char* T8  = (unsigned char*)(ws + 88473600);      //  4,915,200
    // ---- conv-phase overlay (inside T region, dead until NMS) --------------
    double* w1t = (double*)(ws + 39321600);   // 256*512*9*8 = 9,437,184 (transformed)
    double* w2t = (double*)(ws + 48758784);   // 128*256*9*8 = 2,359,296 (transformed)
    double* wgd = (double*)(ws + 51118080);   // 65*128*8    =    66,560
    double* b1d = (double*)(ws + 51184640);   // 2,048
    double* b2d = (double*)(ws + 51186688);   // 1,024
    double* bgd = (double*)(ws + 51187712);   // 1,024 (pad)
    char*   hbase = ws + 51188736;            // batch-group h1/h2 area

    // largest batch-group G with 51,188,736 + G*14,745,600 <= ws_size
    // (G=16 confirmed on hardware in rounds 3-8)
    int G = 1;
    for (int g = 16; g >= 1; g >>= 1) {
        if ((size_t)51188736 + (size_t)g * 14745600 <= ws_size) { G = g; break; }
    }

    // weights -> f64, mfma layout for 3x3 convs
    prep_w<<<(1179648 + 255) / 256, 256, 0, stream>>>(wPa, w1t, 512, 1179648);
    prep_w<<<(294912 + 255) / 256, 256, 0, stream>>>(wPd, w2t, 256, 294912);
    cvt_f32_f64<<<(8320 + 255) / 256, 256, 0, stream>>>(wPg, wgd, 8320);
    cvt_f32_f64<<<1, 256, 0, stream>>>(bPa, b1d, 256);
    cvt_f32_f64<<<1, 256, 0, stream>>>(bPd, b2d, 128);
    cvt_f32_f64<<<1, 256, 0, stream>>>(bPg, bgd, 65);

    for (int bg0 = 0; bg0 < B_; bg0 += G) {
        int Gc = (bg0 + G <= B_) ? G : (B_ - bg0);
        double* h1s = (double*)hbase;                              // Gc*256*4800 f64
        double* h2s = (double*)(hbase + (size_t)G * 9830400);      // Gc*128*4800 f64
        const float* xb = x + (size_t)bg0 * 512 * PIX;
        conv3x3_mfma<512, float, true><<<dim3(30, 4, Gc), 256, 0, stream>>>(xb, w1t, b1d, h1s);
        conv3x3_mfma<256, double, true><<<dim3(30, 2, Gc), 256, 0, stream>>>(h1s, w2t, b2d, h2s);
        conv1x1_softmax_f64<<<dim3(19, Gc), 256, 0, stream>>>(h2s, wgd, bgd, S + (size_t)bg0 * IMG);
    }

    const int NB = NPIX / 256;  // 19200
    hmax9_f64<<<NB, 256, 0, stream>>>(S, T);
    vmax9_eq<<<NB, 256, 0, stream>>>(T, S, M);
    for (int it = 0; it < 2; ++it) {
        hor9_u8<<<NB, 256, 0, stream>>>(M, T8);
        vor9_sup<<<NB, 256, 0, stream>>>(T8, SUP);
        hmax9_supp<<<NB, 256, 0, stream>>>(S, SUP, T);
        vmax9_newmask<<<NB, 256, 0, stream>>>(T, S, SUP, M);
    }
    final_mask<<<NB, 256, 0, stream>>>(S, M, out);
}